// Round 17
// baseline (147.552 us; speedup 1.0000x reference)
//
#include <hip/hip_runtime.h>
#include <hip/hip_bf16.h>
#include <stdint.h>

// Problem constants
#define B_   2
#define S_   2048
#define DIN  1024
#define DOUT 1024
#define H_   16
#define DH_  64

typedef __bf16 bf16_t;
typedef bf16_t bf16x8 __attribute__((ext_vector_type(8)));
typedef float  f32x4  __attribute__((ext_vector_type(4)));

#define WAITV(n) asm volatile("s_waitcnt vmcnt(" #n ")" ::: "memory")

static __device__ __forceinline__ void gld_lds16(const void* g, void* l) {
  __builtin_amdgcn_global_load_lds((const __attribute__((address_space(1))) void*)g,
                                   (__attribute__((address_space(3))) void*)l, 16, 0, 0);
}

static __device__ __forceinline__ unsigned short f2bf(float f) {
  __hip_bfloat16 h = __float2bfloat16(f);
  return __builtin_bit_cast(unsigned short, h);
}

static __device__ __forceinline__ float fexp2(float x) {
#if __has_builtin(__builtin_amdgcn_exp2f)
  return __builtin_amdgcn_exp2f(x);
#else
  return exp2f(x);
#endif
}

// ------ fused prep: z=0..3 transpose+convert W; z=4 convert x -------------
__global__ __launch_bounds__(256) void k_prep(const float* __restrict__ x,
                                              const float* __restrict__ Wq,
                                              const float* __restrict__ Wk,
                                              const float* __restrict__ Wv,
                                              const float* __restrict__ Wo,
                                              unsigned short* __restrict__ xb,
                                              __hip_bfloat16* __restrict__ Wt3,
                                              __hip_bfloat16* __restrict__ Wot) {
  const int tx = threadIdx.x, ty = threadIdx.y;   // block (32,8)
  const int z = blockIdx.z;
  if (z == 4) {
    const int tid = ty * 32 + tx;
    const int base = ((blockIdx.y * 32 + blockIdx.x) * 256 + tid) * 16;
    #pragma unroll
    for (int j = 0; j < 4; ++j) {
      const int i = base + j * 4;
      float4 v = *reinterpret_cast<const float4*>(x + i);
      ushort4 o;
      o.x = f2bf(v.x); o.y = f2bf(v.y); o.z = f2bf(v.z); o.w = f2bf(v.w);
      *reinterpret_cast<ushort4*>(xb + i) = o;
    }
    return;
  }
  __shared__ float tile[32][33];
  const float* src = (z == 0) ? Wq : (z == 1) ? Wk : (z == 2) ? Wv : Wo;
  __hip_bfloat16* dst = (z < 3) ? (Wt3 + (size_t)z * DIN * DOUT) : Wot;
  const int n0 = blockIdx.x * 32, k0 = blockIdx.y * 32;
  #pragma unroll
  for (int i = ty; i < 32; i += 8)
    tile[i][tx] = src[(size_t)(k0 + i) * DOUT + n0 + tx];
  __syncthreads();
  #pragma unroll
  for (int i = ty; i < 32; i += 8)
    dst[(size_t)(n0 + i) * DIN + k0 + tx] = __float2bfloat16(tile[tx][i]);
}

// ---------------- GEMM: C[M,N] = A[M,K] * Bt[N,K]^T  (bf16 MFMA) ----------
// Tile 128 x TN, BK=32. Triple-buffered LDS, counted vmcnt + raw s_barrier
// (T4); stage(t+2) at top of iter t. NW waves per block:
//   NW=8 (QKV): wave owns 32x64 (2 m-frags x 4 n-frags, 8 MFMA/iter);
//     stage = 1 A-chunk + 1 B-chunk per thread, WAITV(2).
//   NW=4 (out-proj, TN=64): wave owns 64x32, WAITV(3).
// MODE 0 (TN=128): scatter to Q*(scale*log2e), K [b,h,s,dh], Vt [b,h,dh,s]
// MODE 1 (TN=64):  Out[m*N+n] = acc + bias[n] (fp32)
template <int MODE, int TN, int NW>
__global__ __launch_bounds__(NW * 64) void k_gemm_bt(
    const __hip_bfloat16* __restrict__ A,    // [M][K]
    const __hip_bfloat16* __restrict__ Bt,   // [N][K]
    __hip_bfloat16* __restrict__ Qb, __hip_bfloat16* __restrict__ Kb,
    __hip_bfloat16* __restrict__ Vtb,
    float* __restrict__ Out, const float* __restrict__ bias,
    int M, int N, int K)
{
  constexpr int NFM = (NW == 8) ? 2 : 4;          // m-frags per wave
  constexpr int NFN = (NW == 8) ? 4 : TN / 32;    // n-frags per wave
  constexpr int WRS = (NW == 8) ? 32 : 64;        // wave row stride
  constexpr int WCS = (NW == 8) ? 64 : TN / 2;    // wave col stride
  __shared__ __align__(16) __hip_bfloat16 As[3][128 * 32];
  __shared__ __align__(16) __hip_bfloat16 Bs[3][TN * 32];
  const int tid = threadIdx.x;
  const int lane = tid & 63, wid = tid >> 6;
  const int r15 = lane & 15, g = lane >> 4;
  const int m0 = blockIdx.x * 128, n0 = blockIdx.y * TN;
  const int wr = wid >> 1, wc = wid & 1;
  f32x4 acc[NFM][NFN] = {};

  auto stage = [&](int bi, int kt) {
    if constexpr (NW == 8) {
      const int d = tid;                          // A: 512 chunks, 1/thread
      const int row = d >> 2, kb = (d & 3) * 8;
      gld_lds16(A + (size_t)(m0 + row) * K + kt + kb, (void*)(As[bi] + (size_t)(d & ~63) * 8));
      gld_lds16(Bt + (size_t)(n0 + row) * K + kt + kb, (void*)(Bs[bi] + (size_t)(d & ~63) * 8));
    } else {
      #pragma unroll
      for (int i = 0; i < 2; ++i) {               // A: 512 chunks, 2/thread
        const int c = i * 256 + tid;
        const int row = c >> 2, kb = (c & 3) * 8;
        gld_lds16(A + (size_t)(m0 + row) * K + kt + kb, (void*)(As[bi] + (size_t)(c & ~63) * 8));
      }
      const int c = tid;                          // B: 256 chunks, 1/thread
      const int row = c >> 2, kb = (c & 3) * 8;
      gld_lds16(Bt + (size_t)(n0 + row) * K + kt + kb, (void*)(Bs[bi] + (size_t)(c & ~63) * 8));
    }
  };

  const int NT = K >> 5;                          // K-tiles of 32
  stage(0, 0); stage(1, 32);
  if constexpr (NW == 8) WAITV(2); else WAITV(3); // tile0 landed
  __builtin_amdgcn_s_barrier();

  int bi = 0;
  for (int t = 0; t < NT; ++t) {
    int bs = bi + 2; if (bs >= 3) bs -= 3;
    const bool st = (t + 2 < NT);
    if (st) stage(bs, (t + 2) * 32);              // prefetch depth 2
    bf16x8 af[NFM], bfr[NFN];
    #pragma unroll
    for (int mi = 0; mi < NFM; ++mi)
      af[mi] = *reinterpret_cast<const bf16x8*>(As[bi] + (wr * WRS + mi * 16 + r15) * 32 + g * 8);
    #pragma unroll
    for (int ni = 0; ni < NFN; ++ni)
      bfr[ni] = *reinterpret_cast<const bf16x8*>(Bs[bi] + (wc * WCS + ni * 16 + r15) * 32 + g * 8);
    __builtin_amdgcn_s_setprio(1);
    #pragma unroll
    for (int mi = 0; mi < NFM; ++mi)
      #pragma unroll
      for (int ni = 0; ni < NFN; ++ni)
        acc[mi][ni] = __builtin_amdgcn_mfma_f32_16x16x32_bf16(af[mi], bfr[ni], acc[mi][ni], 0, 0, 0);
    __builtin_amdgcn_s_setprio(0);
    if (t + 1 < NT) {
      if (st) { if constexpr (NW == 8) WAITV(2); else WAITV(3); }
      else    { WAITV(0); }                       // tile t+1 landed
      __builtin_amdgcn_s_barrier();
    }
    bi = (bi + 1 == 3) ? 0 : bi + 1;
  }

  // Epilogue. C/D layout: col = lane&15, row = (lane>>4)*4 + reg  [m89/m91]
  #pragma unroll
  for (int mi = 0; mi < NFM; ++mi) {
    #pragma unroll
    for (int ni = 0; ni < NFN; ++ni) {
      const int mb = m0 + wr * WRS + mi * 16 + g * 4;   // 4 consecutive m
      const int n  = n0 + wc * WCS + ni * 16 + r15;
      if (MODE == 0) {
        const int w = n >> 10, nn = n & 1023;           // wave-uniform per frag
        const int h = nn >> 6, dh = nn & 63;
        const int b = mb >> 11, s = mb & 2047;
        const size_t bh = (size_t)(b * H_ + h);
        if (w == 2) {
          ushort4 pv;
          pv.x = f2bf(acc[mi][ni][0]); pv.y = f2bf(acc[mi][ni][1]);
          pv.z = f2bf(acc[mi][ni][2]); pv.w = f2bf(acc[mi][ni][3]);
          *reinterpret_cast<ushort4*>((unsigned short*)Vtb + (bh * DH_ + dh) * S_ + s) = pv;
        } else {
          #pragma unroll
          for (int rr = 0; rr < 4; ++rr) {
            float v = acc[mi][ni][rr];
            if (w == 0) v *= 0.022097086912079608f * 1.4426950408889634f;
            const __hip_bfloat16 hv = __float2bfloat16(v);
            if (w == 0) Qb[(bh * S_ + s + rr) * DH_ + dh] = hv;
            else        Kb[(bh * S_ + s + rr) * DH_ + dh] = hv;
          }
        }
      } else {
        #pragma unroll
        for (int rr = 0; rr < 4; ++rr)
          Out[(size_t)(mb + rr) * N + n] = acc[mi][ni][rr] + bias[n];
      }
    }
  }
}

// ---------------- flash attention (K staged, V direct-from-L2) ------------
// grid (B*H, S/64); bh FAST dim -> XCD affinity. qb = 31-blockIdx.y
// (heavy-first). 4 waves x 16 q, KVBLK=64. K double-buffered via
// global_load_lds (pre-swizzled source, rule #21) — K feeds the immediate
// QK^T MFMA so it MUST be staged (R5 lesson). V is consumed ~400cy into the
// iteration (after QK^T + softmax) -> per-lane GLOBAL loads issued at the
// top of the iteration have their L2 latency fully covered; no Vs staging.
// LDS 40KB -> 24KB (4 -> 6 blocks/CU), stage 4 -> 2 loads/thread, V's 8
// ds_read_b128/lane/tile leave the LDS pipe. Swapped QK^T -> D[kv][q],
// lane-local fixed-max exp2 softmax, P via per-wave LDS, denom reduce once.
__global__ __launch_bounds__(256) void k_attn(
    const __hip_bfloat16* __restrict__ Qb,
    const __hip_bfloat16* __restrict__ Kb,
    const __hip_bfloat16* __restrict__ Vtb,
    __hip_bfloat16* __restrict__ Ctx)
{
  __shared__ __align__(16) __hip_bfloat16 Ks[2][64 * 64];   // [kv][dh] 8KB x2
  __shared__ __align__(16) unsigned short Pl[4][16 * 64];   // per-wave 2KB
  const int tid = threadIdx.x, lane = tid & 63, w = tid >> 6;
  const int r15 = lane & 15, g = lane >> 4;
  const int bh = blockIdx.x;
  const int b = bh >> 4, h = bh & 15;
  const int qb = 31 - blockIdx.y;
  const __hip_bfloat16* Qh = Qb  + (size_t)bh * S_ * DH_;
  const __hip_bfloat16* Kh = Kb  + (size_t)bh * S_ * DH_;
  const __hip_bfloat16* Vh = Vtb + (size_t)bh * DH_ * S_;
  char* PlW = (char*)&Pl[w][0];
  const int sw = (r15 & 7);
  const float FIXM = 4.0f;

  auto stage = [&](int bufi, int t) {
    const int kv0 = t * 64;
    #pragma unroll
    for (int i = 0; i < 2; ++i) {
      const int c = i * 256 + tid;               // K: 512 chunks, 2/thread
      const int r = c >> 3;
      const int scc = (c & 7) ^ (r & 7);
      const int cbase = i * 256 + w * 64;
      gld_lds16(Kh + (size_t)(kv0 + r) * DH_ + scc * 8, (void*)(Ks[bufi] + cbase * 8));
    }
  };

  const int q = qb * 64 + w * 16 + r15;

  bf16x8 qf[2];
  #pragma unroll
  for (int ks = 0; ks < 2; ++ks)
    qf[ks] = *reinterpret_cast<const bf16x8*>(Qh + (size_t)q * DH_ + ks * 32 + g * 8);

  f32x4 of[4] = {};
  float lrow = 0.f;

  const int nt = qb + 1;
  stage(0, 0);
  __syncthreads();

  for (int t = 0; t < nt; ++t) {
    const int cur = t & 1;
    if (t + 1 < nt) stage(cur ^ 1, t + 1);
    const char* Kb_ = (const char*)Ks[cur];
    const int kv0 = t * 64;

    // V fragments DIRECT from global (L2-resident, XCD-affine); issued here,
    // consumed after QK^T + softmax -> latency covered.
    bf16x8 vf[2][4];
    #pragma unroll
    for (int ks = 0; ks < 2; ++ks)
      #pragma unroll
      for (int d = 0; d < 4; ++d)
        vf[ks][d] = *reinterpret_cast<const bf16x8*>(
            Vh + (size_t)(d * 16 + r15) * S_ + kv0 + ks * 32 + g * 8);

    f32x4 sf[4] = {};
    __builtin_amdgcn_s_setprio(1);
    #pragma unroll
    for (int ks = 0; ks < 2; ++ks)
      #pragma unroll
      for (int c = 0; c < 4; ++c) {
        bf16x8 kf = *reinterpret_cast<const bf16x8*>(
            Kb_ + (c * 16 + r15) * 128 + (((ks * 4 + g) ^ sw) * 16));
        sf[c] = __builtin_amdgcn_mfma_f32_16x16x32_bf16(kf, qf[ks], sf[c], 0, 0, 0);
      }
    __builtin_amdgcn_s_setprio(0);

    float pv[16];
    #pragma unroll
    for (int c = 0; c < 4; ++c)
      #pragma unroll
      for (int r = 0; r < 4; ++r)
        pv[c * 4 + r] = sf[c][r];
    if (t == qb) {
      #pragma unroll
      for (int c = 0; c < 4; ++c)
        #pragma unroll
        for (int r = 0; r < 4; ++r) {
          const int kv = kv0 + c * 16 + g * 4 + r;
          if (kv > q) pv[c * 4 + r] = -INFINITY;
        }
    }
    float pe[16];
    #pragma unroll
    for (int j = 0; j < 16; ++j) pe[j] = fexp2(pv[j] - FIXM);
    #pragma unroll
    for (int c = 0; c < 4; ++c) {
      ushort4 pw;
      pw.x = f2bf(pe[c * 4 + 0]); pw.y = f2bf(pe[c * 4 + 1]);
      pw.z = f2bf(pe[c * 4 + 2]); pw.w = f2bf(pe[c * 4 + 3]);
      const int chunk = (c * 2 + (g >> 1)) ^ sw;
      *reinterpret_cast<ushort4*>(PlW + r15 * 128 + chunk * 16 + (g & 1) * 8) = pw;
    }
    float s8[8], s4[4];
    #pragma unroll
    for (int j = 0; j < 8; ++j) s8[j] = pe[j] + pe[j + 8];
    #pragma unroll
    for (int j = 0; j < 4; ++j) s4[j] = s8[j] + s8[j + 4];
    lrow += (s4[0] + s4[1]) + (s4[2] + s4[3]);

    __builtin_amdgcn_s_setprio(1);
    #pragma unroll
    for (int ks = 0; ks < 2; ++ks) {
      bf16x8 pf = *reinterpret_cast<const bf16x8*>(
          PlW + r15 * 128 + (((ks * 4 + g) ^ sw) * 16));
      #pragma unroll
      for (int d = 0; d < 4; ++d)
        of[d] = __builtin_amdgcn_mfma_f32_16x16x32_bf16(vf[ks][d], pf, of[d], 0, 0, 0);
    }
    __builtin_amdgcn_s_setprio(0);
    __syncthreads();
  }

  lrow += __shfl_xor(lrow, 16, 64);
  lrow += __shfl_xor(lrow, 32, 64);

  const float inv = 1.0f / lrow;
  unsigned short* Cp = (unsigned short*)Ctx + ((size_t)(b * S_ + q) * H_ + h) * DH_;
  #pragma unroll
  for (int d = 0; d < 4; ++d) {
    ushort4 ov;
    ov.x = f2bf(of[d][0] * inv); ov.y = f2bf(of[d][1] * inv);
    ov.z = f2bf(of[d][2] * inv); ov.w = f2bf(of[d][3] * inv);
    *reinterpret_cast<ushort4*>(Cp + d * 16 + g * 4) = ov;
  }
}

// --------------------------------- launch --------------------------------
extern "C" void kernel_launch(void* const* d_in, const int* in_sizes, int n_in,
                              void* d_out, int out_size, void* d_ws, size_t ws_size,
                              hipStream_t stream) {
  const float* x  = (const float*)d_in[0];
  const float* Wq = (const float*)d_in[1];
  const float* Wk = (const float*)d_in[2];
  const float* Wv = (const float*)d_in[3];
  const float* Wo = (const float*)d_in[4];
  const float* bo = (const float*)d_in[5];
  float* out = (float*)d_out;

  uint8_t* ws = (uint8_t*)d_ws;
  __hip_bfloat16* xb  = (__hip_bfloat16*)(ws);
  __hip_bfloat16* Wt3 = (__hip_bfloat16*)(ws + 8388608);
  __hip_bfloat16* Wot = (__hip_bfloat16*)(ws + 14680064);
  __hip_bfloat16* Qb  = (__hip_bfloat16*)(ws + 16777216);
  __hip_bfloat16* Kb  = (__hip_bfloat16*)(ws + 25165824);
  __hip_bfloat16* Vtb = (__hip_bfloat16*)(ws + 33554432);
  __hip_bfloat16* Ctx = (__hip_bfloat16*)(ws + 41943040);

  // fused prep: z=0..3 transpose Wq/Wk/Wv/Wo, z=4 convert x
  k_prep<<<dim3(32, 32, 5), dim3(32, 8), 0, stream>>>(x, Wq, Wk, Wv, Wo,
                                                      (unsigned short*)xb, Wt3, Wot);
  // fused QKV: A = xb [4096,1024], Bt = [Wq^T|Wk^T|Wv^T] [3072,1024]
  k_gemm_bt<0, 128, 8><<<dim3(32, 24), 512, 0, stream>>>(xb, Wt3, Qb, Kb, Vtb, nullptr, nullptr,
                                                         4096, 3072, 1024);
  k_attn<<<dim3(32, 32), 256, 0, stream>>>(Qb, Kb, Vtb, Ctx);
  // out = Ctx @ Wo + bo  (fp32 out), tile 128x64 -> 512 blocks
  k_gemm_bt<1, 64, 4><<<dim3(32, 16), 256, 0, stream>>>(Ctx, Wot, nullptr, nullptr, nullptr,
                                                        out, bo, 4096, 1024, 1024);
}

// Round 18
// 106.799 us; speedup vs baseline: 1.3816x; 1.3816x over previous
//
#include <hip/hip_runtime.h>
#include <hip/hip_bf16.h>
#include <stdint.h>

// Problem constants
#define B_   2
#define S_   2048
#define DIN  1024
#define DOUT 1024
#define H_   16
#define DH_  64

typedef __bf16 bf16_t;
typedef bf16_t bf16x8 __attribute__((ext_vector_type(8)));
typedef float  f32x4  __attribute__((ext_vector_type(4)));

#define WAITV(n) asm volatile("s_waitcnt vmcnt(" #n ")" ::: "memory")

static __device__ __forceinline__ void gld_lds16(const void* g, void* l) {
  __builtin_amdgcn_global_load_lds((const __attribute__((address_space(1))) void*)g,
                                   (__attribute__((address_space(3))) void*)l, 16, 0, 0);
}

static __device__ __forceinline__ unsigned short f2bf(float f) {
  __hip_bfloat16 h = __float2bfloat16(f);
  return __builtin_bit_cast(unsigned short, h);
}

static __device__ __forceinline__ float fexp2(float x) {
#if __has_builtin(__builtin_amdgcn_exp2f)
  return __builtin_amdgcn_exp2f(x);
#else
  return exp2f(x);
#endif
}

// ------ fused prep: z=0..3 transpose+convert W; z=4 convert x -------------
__global__ __launch_bounds__(256) void k_prep(const float* __restrict__ x,
                                              const float* __restrict__ Wq,
                                              const float* __restrict__ Wk,
                                              const float* __restrict__ Wv,
                                              const float* __restrict__ Wo,
                                              unsigned short* __restrict__ xb,
                                              __hip_bfloat16* __restrict__ Wt3,
                                              __hip_bfloat16* __restrict__ Wot) {
  const int tx = threadIdx.x, ty = threadIdx.y;   // block (32,8)
  const int z = blockIdx.z;
  if (z == 4) {
    const int tid = ty * 32 + tx;
    const int base = ((blockIdx.y * 32 + blockIdx.x) * 256 + tid) * 16;
    #pragma unroll
    for (int j = 0; j < 4; ++j) {
      const int i = base + j * 4;
      float4 v = *reinterpret_cast<const float4*>(x + i);
      ushort4 o;
      o.x = f2bf(v.x); o.y = f2bf(v.y); o.z = f2bf(v.z); o.w = f2bf(v.w);
      *reinterpret_cast<ushort4*>(xb + i) = o;
    }
    return;
  }
  __shared__ float tile[32][33];
  const float* src = (z == 0) ? Wq : (z == 1) ? Wk : (z == 2) ? Wv : Wo;
  __hip_bfloat16* dst = (z < 3) ? (Wt3 + (size_t)z * DIN * DOUT) : Wot;
  const int n0 = blockIdx.x * 32, k0 = blockIdx.y * 32;
  #pragma unroll
  for (int i = ty; i < 32; i += 8)
    tile[i][tx] = src[(size_t)(k0 + i) * DOUT + n0 + tx];
  __syncthreads();
  #pragma unroll
  for (int i = ty; i < 32; i += 8)
    dst[(size_t)(n0 + i) * DIN + k0 + tx] = __float2bfloat16(tile[tx][i]);
}

// ---------------- GEMM: C[M,N] = A[M,K] * Bt[N,K]^T  (bf16 MFMA) ----------
// Tile 128 x TN, BK=32, 4 waves. Triple-buffered LDS, counted vmcnt +
// raw s_barrier (T4); stage(t+2) at top of iter t.
// MODE 0 (TN=128): scatter to Q*(scale*log2e), K [b,h,s,dh], Vt [b,h,dh,s]
// MODE 1 (TN=64):  Out[m*N+n] = acc + bias[n] (fp32)
template <int MODE, int TN>
__global__ __launch_bounds__(256) void k_gemm_bt(
    const __hip_bfloat16* __restrict__ A,    // [M][K]
    const __hip_bfloat16* __restrict__ Bt,   // [N][K]
    __hip_bfloat16* __restrict__ Qb, __hip_bfloat16* __restrict__ Kb,
    __hip_bfloat16* __restrict__ Vtb,
    float* __restrict__ Out, const float* __restrict__ bias,
    int M, int N, int K)
{
  constexpr int NFRAG = TN / 32;                  // per-wave n fragments
  __shared__ __align__(16) __hip_bfloat16 As[3][128 * 32];
  __shared__ __align__(16) __hip_bfloat16 Bs[3][TN * 32];
  const int tid = threadIdx.x;
  const int lane = tid & 63, wid = tid >> 6;
  const int r15 = lane & 15, g = lane >> 4;
  const int m0 = blockIdx.x * 128, n0 = blockIdx.y * TN;
  const int wr = wid >> 1, wc = wid & 1;          // wave owns 64 x TN/2
  f32x4 acc[4][NFRAG] = {};

  auto stage = [&](int bi, int kt) {
    #pragma unroll
    for (int i = 0; i < 2; ++i) {                 // A: 512 chunks, 2/thread
      const int c = i * 256 + tid;
      const int row = c >> 2, kb = (c & 3) * 8;
      gld_lds16(A + (size_t)(m0 + row) * K + kt + kb, (void*)(As[bi] + (size_t)(c & ~63) * 8));
    }
    if constexpr (TN == 128) {
      #pragma unroll
      for (int i = 0; i < 2; ++i) {
        const int c = i * 256 + tid;
        const int row = c >> 2, kb = (c & 3) * 8;
        gld_lds16(Bt + (size_t)(n0 + row) * K + kt + kb, (void*)(Bs[bi] + (size_t)(c & ~63) * 8));
      }
    } else {
      const int c = tid;                          // B: 256 chunks, 1/thread
      const int row = c >> 2, kb = (c & 3) * 8;
      gld_lds16(Bt + (size_t)(n0 + row) * K + kt + kb, (void*)(Bs[bi] + (size_t)(c & ~63) * 8));
    }
  };

  const int NT = K >> 5;                          // K-tiles of 32
  stage(0, 0); stage(1, 32);
  if constexpr (TN == 128) WAITV(4); else WAITV(3);   // tile0 landed
  __builtin_amdgcn_s_barrier();

  int bi = 0;
  for (int t = 0; t < NT; ++t) {
    int bs = bi + 2; if (bs >= 3) bs -= 3;
    const bool st = (t + 2 < NT);
    if (st) stage(bs, (t + 2) * 32);              // prefetch depth 2
    bf16x8 af[4], bfr[NFRAG];
    #pragma unroll
    for (int mi = 0; mi < 4; ++mi)
      af[mi] = *reinterpret_cast<const bf16x8*>(As[bi] + (wr * 64 + mi * 16 + r15) * 32 + g * 8);
    #pragma unroll
    for (int ni = 0; ni < NFRAG; ++ni)
      bfr[ni] = *reinterpret_cast<const bf16x8*>(Bs[bi] + (wc * (TN / 2) + ni * 16 + r15) * 32 + g * 8);
    __builtin_amdgcn_s_setprio(1);
    #pragma unroll
    for (int mi = 0; mi < 4; ++mi)
      #pragma unroll
      for (int ni = 0; ni < NFRAG; ++ni)
        acc[mi][ni] = __builtin_amdgcn_mfma_f32_16x16x32_bf16(af[mi], bfr[ni], acc[mi][ni], 0, 0, 0);
    __builtin_amdgcn_s_setprio(0);
    if (t + 1 < NT) {
      if (st) { if constexpr (TN == 128) WAITV(4); else WAITV(3); }
      else    { WAITV(0); }                       // tile t+1 landed
      __builtin_amdgcn_s_barrier();
    }
    bi = (bi + 1 == 3) ? 0 : bi + 1;
  }

  // Epilogue. C/D layout: col = lane&15, row = (lane>>4)*4 + reg  [m89/m91]
  #pragma unroll
  for (int mi = 0; mi < 4; ++mi) {
    #pragma unroll
    for (int ni = 0; ni < NFRAG; ++ni) {
      const int mb = m0 + wr * 64 + mi * 16 + g * 4;    // 4 consecutive m
      const int n  = n0 + wc * (TN / 2) + ni * 16 + r15;
      if (MODE == 0) {
        const int w = n >> 10, nn = n & 1023;           // wave-uniform per frag
        const int h = nn >> 6, dh = nn & 63;
        const int b = mb >> 11, s = mb & 2047;
        const size_t bh = (size_t)(b * H_ + h);
        if (w == 2) {
          ushort4 pv;
          pv.x = f2bf(acc[mi][ni][0]); pv.y = f2bf(acc[mi][ni][1]);
          pv.z = f2bf(acc[mi][ni][2]); pv.w = f2bf(acc[mi][ni][3]);
          *reinterpret_cast<ushort4*>((unsigned short*)Vtb + (bh * DH_ + dh) * S_ + s) = pv;
        } else {
          #pragma unroll
          for (int rr = 0; rr < 4; ++rr) {
            float v = acc[mi][ni][rr];
            if (w == 0) v *= 0.022097086912079608f * 1.4426950408889634f;
            const __hip_bfloat16 hv = __float2bfloat16(v);
            if (w == 0) Qb[(bh * S_ + s + rr) * DH_ + dh] = hv;
            else        Kb[(bh * S_ + s + rr) * DH_ + dh] = hv;
          }
        }
      } else {
        #pragma unroll
        for (int rr = 0; rr < 4; ++rr)
          Out[(size_t)(mb + rr) * N + n] = acc[mi][ni][rr] + bias[n];
      }
    }
  }
}

// ---------------- flash attention (R8/R13-measured best: 42.5 us) ---------
// grid (B*H, S/64); bh FAST dim -> XCD affinity. qb = 31-blockIdx.y
// (heavy-first). 4 waves x 16 q, KVBLK=64, K/V double-buffered via
// global_load_lds (pre-swizzled source, rule #21). Swapped QK^T -> D[kv][q],
// lane-local fixed-max exp2 softmax, P via per-wave LDS, denom reduce once.
__global__ __launch_bounds__(256) void k_attn(
    const __hip_bfloat16* __restrict__ Qb,
    const __hip_bfloat16* __restrict__ Kb,
    const __hip_bfloat16* __restrict__ Vtb,
    __hip_bfloat16* __restrict__ Ctx)
{
  __shared__ __align__(16) __hip_bfloat16 Ks[2][64 * 64];
  __shared__ __align__(16) __hip_bfloat16 Vs[2][64 * 64];
  __shared__ __align__(16) unsigned short Pl[4][16 * 64];
  const int tid = threadIdx.x, lane = tid & 63, w = tid >> 6;
  const int r15 = lane & 15, g = lane >> 4;
  const int bh = blockIdx.x;
  const int b = bh >> 4, h = bh & 15;
  const int qb = 31 - blockIdx.y;
  const __hip_bfloat16* Qh = Qb  + (size_t)bh * S_ * DH_;
  const __hip_bfloat16* Kh = Kb  + (size_t)bh * S_ * DH_;
  const __hip_bfloat16* Vh = Vtb + (size_t)bh * DH_ * S_;
  char* PlW = (char*)&Pl[w][0];
  const int sw = (r15 & 7);
  const float FIXM = 4.0f;

  auto stage = [&](int bufi, int t) {
    const int kv0 = t * 64;
    #pragma unroll
    for (int i = 0; i < 2; ++i) {
      const int c = i * 256 + tid;
      const int r = c >> 3;
      const int scc = (c & 7) ^ (r & 7);
      const int cbase = i * 256 + w * 64;
      gld_lds16(Kh + (size_t)(kv0 + r) * DH_ + scc * 8, (void*)(Ks[bufi] + cbase * 8));
      gld_lds16(Vh + (size_t)r * S_ + kv0 + scc * 8,    (void*)(Vs[bufi] + cbase * 8));
    }
  };

  const int q = qb * 64 + w * 16 + r15;

  bf16x8 qf[2];
  #pragma unroll
  for (int ks = 0; ks < 2; ++ks)
    qf[ks] = *reinterpret_cast<const bf16x8*>(Qh + (size_t)q * DH_ + ks * 32 + g * 8);

  f32x4 of[4] = {};
  float lrow = 0.f;

  const int nt = qb + 1;
  stage(0, 0);
  __syncthreads();

  for (int t = 0; t < nt; ++t) {
    const int cur = t & 1;
    if (t + 1 < nt) stage(cur ^ 1, t + 1);
    const char* Kb_ = (const char*)Ks[cur];
    const char* Vb_ = (const char*)Vs[cur];
    const int kv0 = t * 64;

    f32x4 sf[4] = {};
    __builtin_amdgcn_s_setprio(1);
    #pragma unroll
    for (int ks = 0; ks < 2; ++ks)
      #pragma unroll
      for (int c = 0; c < 4; ++c) {
        bf16x8 kf = *reinterpret_cast<const bf16x8*>(
            Kb_ + (c * 16 + r15) * 128 + (((ks * 4 + g) ^ sw) * 16));
        sf[c] = __builtin_amdgcn_mfma_f32_16x16x32_bf16(kf, qf[ks], sf[c], 0, 0, 0);
      }
    __builtin_amdgcn_s_setprio(0);

    float pv[16];
    #pragma unroll
    for (int c = 0; c < 4; ++c)
      #pragma unroll
      for (int r = 0; r < 4; ++r)
        pv[c * 4 + r] = sf[c][r];
    if (t == qb) {
      #pragma unroll
      for (int c = 0; c < 4; ++c)
        #pragma unroll
        for (int r = 0; r < 4; ++r) {
          const int kv = kv0 + c * 16 + g * 4 + r;
          if (kv > q) pv[c * 4 + r] = -INFINITY;
        }
    }
    float pe[16];
    #pragma unroll
    for (int j = 0; j < 16; ++j) pe[j] = fexp2(pv[j] - FIXM);
    #pragma unroll
    for (int c = 0; c < 4; ++c) {
      ushort4 pw;
      pw.x = f2bf(pe[c * 4 + 0]); pw.y = f2bf(pe[c * 4 + 1]);
      pw.z = f2bf(pe[c * 4 + 2]); pw.w = f2bf(pe[c * 4 + 3]);
      const int chunk = (c * 2 + (g >> 1)) ^ sw;
      *reinterpret_cast<ushort4*>(PlW + r15 * 128 + chunk * 16 + (g & 1) * 8) = pw;
    }
    float s8[8], s4[4];
    #pragma unroll
    for (int j = 0; j < 8; ++j) s8[j] = pe[j] + pe[j + 8];
    #pragma unroll
    for (int j = 0; j < 4; ++j) s4[j] = s8[j] + s8[j + 4];
    lrow += (s4[0] + s4[1]) + (s4[2] + s4[3]);

    __builtin_amdgcn_s_setprio(1);
    #pragma unroll
    for (int ks = 0; ks < 2; ++ks) {
      bf16x8 pf = *reinterpret_cast<const bf16x8*>(
          PlW + r15 * 128 + (((ks * 4 + g) ^ sw) * 16));
      #pragma unroll
      for (int d = 0; d < 4; ++d) {
        bf16x8 vf = *reinterpret_cast<const bf16x8*>(
            Vb_ + (d * 16 + r15) * 128 + (((ks * 4 + g) ^ sw) * 16));
        of[d] = __builtin_amdgcn_mfma_f32_16x16x32_bf16(vf, pf, of[d], 0, 0, 0);
      }
    }
    __builtin_amdgcn_s_setprio(0);
    __syncthreads();
  }

  lrow += __shfl_xor(lrow, 16, 64);
  lrow += __shfl_xor(lrow, 32, 64);

  const float inv = 1.0f / lrow;
  unsigned short* Cp = (unsigned short*)Ctx + ((size_t)(b * S_ + q) * H_ + h) * DH_;
  #pragma unroll
  for (int d = 0; d < 4; ++d) {
    ushort4 ov;
    ov.x = f2bf(of[d][0] * inv); ov.y = f2bf(of[d][1] * inv);
    ov.z = f2bf(of[d][2] * inv); ov.w = f2bf(of[d][3] * inv);
    *reinterpret_cast<ushort4*>(Cp + d * 16 + g * 4) = ov;
  }
}

// --------------------------------- launch --------------------------------
extern "C" void kernel_launch(void* const* d_in, const int* in_sizes, int n_in,
                              void* d_out, int out_size, void* d_ws, size_t ws_size,
                              hipStream_t stream) {
  const float* x  = (const float*)d_in[0];
  const float* Wq = (const float*)d_in[1];
  const float* Wk = (const float*)d_in[2];
  const float* Wv = (const float*)d_in[3];
  const float* Wo = (const float*)d_in[4];
  const float* bo = (const float*)d_in[5];
  float* out = (float*)d_out;

  uint8_t* ws = (uint8_t*)d_ws;
  __hip_bfloat16* xb  = (__hip_bfloat16*)(ws);
  __hip_bfloat16* Wt3 = (__hip_bfloat16*)(ws + 8388608);
  __hip_bfloat16* Wot = (__hip_bfloat16*)(ws + 14680064);
  __hip_bfloat16* Qb  = (__hip_bfloat16*)(ws + 16777216);
  __hip_bfloat16* Kb  = (__hip_bfloat16*)(ws + 25165824);
  __hip_bfloat16* Vtb = (__hip_bfloat16*)(ws + 33554432);
  __hip_bfloat16* Ctx = (__hip_bfloat16*)(ws + 41943040);

  // fused prep: z=0..3 transpose Wq/Wk/Wv/Wo, z=4 convert x
  k_prep<<<dim3(32, 32, 5), dim3(32, 8), 0, stream>>>(x, Wq, Wk, Wv, Wo,
                                                      (unsigned short*)xb, Wt3, Wot);
  // fused QKV: A = xb [4096,1024], Bt = [Wq^T|Wk^T|Wv^T] [3072,1024]
  k_gemm_bt<0, 128><<<dim3(32, 24), 256, 0, stream>>>(xb, Wt3, Qb, Kb, Vtb, nullptr, nullptr,
                                                      4096, 3072, 1024);
  k_attn<<<dim3(32, 32), 256, 0, stream>>>(Qb, Kb, Vtb, Ctx);
  // out = Ctx @ Wo + bo  (fp32 out), tile 128x64 -> 512 blocks
  k_gemm_bt<1, 64><<<dim3(32, 16), 256, 0, stream>>>(Ctx, Wot, nullptr, nullptr, nullptr,
                                                     out, bo, 4096, 1024, 1024);
}

// Round 19
// 104.819 us; speedup vs baseline: 1.4077x; 1.0189x over previous
//
#include <hip/hip_runtime.h>
#include <hip/hip_bf16.h>
#include <stdint.h>

// Problem constants
#define B_   2
#define S_   2048
#define DIN  1024
#define DOUT 1024
#define H_   16
#define DH_  64

typedef __bf16 bf16_t;
typedef bf16_t bf16x8 __attribute__((ext_vector_type(8)));
typedef float  f32x4  __attribute__((ext_vector_type(4)));

#define WAITV(n) asm volatile("s_waitcnt vmcnt(" #n ")" ::: "memory")

static __device__ __forceinline__ void gld_lds16(const void* g, void* l) {
  __builtin_amdgcn_global_load_lds((const __attribute__((address_space(1))) void*)g,
                                   (__attribute__((address_space(3))) void*)l, 16, 0, 0);
}

static __device__ __forceinline__ unsigned short f2bf(float f) {
  __hip_bfloat16 h = __float2bfloat16(f);
  return __builtin_bit_cast(unsigned short, h);
}

static __device__ __forceinline__ float fexp2(float x) {
#if __has_builtin(__builtin_amdgcn_exp2f)
  return __builtin_amdgcn_exp2f(x);
#else
  return exp2f(x);
#endif
}

// ------ fused prep: z=0..3 transpose+convert W (64x64 tiles); z=4 convert x
// transpose: 1024 blocks (16x16x4), block (32,8), LDS 64x65 fp32 (16.6KB,
//   stride-65 -> conflict-free), coalesced 2x128B reads/row, 2B/lane writes.
// convert x: 256 blocks (z=4), 16 grid-strided float4 per thread.
__global__ __launch_bounds__(256) void k_prep(const float* __restrict__ x,
                                              const float* __restrict__ Wq,
                                              const float* __restrict__ Wk,
                                              const float* __restrict__ Wv,
                                              const float* __restrict__ Wo,
                                              unsigned short* __restrict__ xb,
                                              __hip_bfloat16* __restrict__ Wt3,
                                              __hip_bfloat16* __restrict__ Wot) {
  const int tx = threadIdx.x, ty = threadIdx.y;   // block (32,8)
  const int z = blockIdx.z;
  if (z == 4) {
    if (blockIdx.x >= 16) return;                 // 256 blocks used
    const int bid = blockIdx.y * 16 + blockIdx.x;
    const int tid = ty * 32 + tx;
    #pragma unroll
    for (int j = 0; j < 16; ++j) {
      const int idx = j * 65536 + bid * 256 + tid;   // float4 index
      const int i = idx * 4;
      float4 v = *reinterpret_cast<const float4*>(x + i);
      ushort4 o;
      o.x = f2bf(v.x); o.y = f2bf(v.y); o.z = f2bf(v.z); o.w = f2bf(v.w);
      *reinterpret_cast<ushort4*>(xb + i) = o;
    }
    return;
  }
  __shared__ float tile[64][65];
  const float* src = (z == 0) ? Wq : (z == 1) ? Wk : (z == 2) ? Wv : Wo;
  __hip_bfloat16* dst = (z < 3) ? (Wt3 + (size_t)z * DIN * DOUT) : Wot;
  const int n0 = blockIdx.x * 64, k0 = blockIdx.y * 64;
  #pragma unroll
  for (int i = ty; i < 64; i += 8) {
    tile[i][tx]      = src[(size_t)(k0 + i) * DOUT + n0 + tx];
    tile[i][tx + 32] = src[(size_t)(k0 + i) * DOUT + n0 + tx + 32];
  }
  __syncthreads();
  #pragma unroll
  for (int i = ty; i < 64; i += 8) {
    // dst[n0+i][k0+tx], dst[n0+i][k0+tx+32] ; tile[k][n]: value = W[k][n]
    dst[(size_t)(n0 + i) * DIN + k0 + tx]      = __float2bfloat16(tile[tx][i]);
    dst[(size_t)(n0 + i) * DIN + k0 + tx + 32] = __float2bfloat16(tile[tx + 32][i]);
  }
}

// ---------------- GEMM: C[M,N] = A[M,K] * Bt[N,K]^T  (bf16 MFMA) ----------
// Tile 128 x TN, BK=32, 4 waves. Triple-buffered LDS, counted vmcnt +
// raw s_barrier (T4); stage(t+2) at top of iter t.
// MODE 0 (TN=128): scatter to Q*(scale*log2e), K [b,h,s,dh], Vt [b,h,dh,s]
// MODE 1 (TN=64):  Out[m*N+n] = acc + bias[n] (fp32)
template <int MODE, int TN>
__global__ __launch_bounds__(256) void k_gemm_bt(
    const __hip_bfloat16* __restrict__ A,    // [M][K]
    const __hip_bfloat16* __restrict__ Bt,   // [N][K]
    __hip_bfloat16* __restrict__ Qb, __hip_bfloat16* __restrict__ Kb,
    __hip_bfloat16* __restrict__ Vtb,
    float* __restrict__ Out, const float* __restrict__ bias,
    int M, int N, int K)
{
  constexpr int NFRAG = TN / 32;                  // per-wave n fragments
  __shared__ __align__(16) __hip_bfloat16 As[3][128 * 32];
  __shared__ __align__(16) __hip_bfloat16 Bs[3][TN * 32];
  const int tid = threadIdx.x;
  const int lane = tid & 63, wid = tid >> 6;
  const int r15 = lane & 15, g = lane >> 4;
  const int m0 = blockIdx.x * 128, n0 = blockIdx.y * TN;
  const int wr = wid >> 1, wc = wid & 1;          // wave owns 64 x TN/2
  f32x4 acc[4][NFRAG] = {};

  auto stage = [&](int bi, int kt) {
    #pragma unroll
    for (int i = 0; i < 2; ++i) {                 // A: 512 chunks, 2/thread
      const int c = i * 256 + tid;
      const int row = c >> 2, kb = (c & 3) * 8;
      gld_lds16(A + (size_t)(m0 + row) * K + kt + kb, (void*)(As[bi] + (size_t)(c & ~63) * 8));
    }
    if constexpr (TN == 128) {
      #pragma unroll
      for (int i = 0; i < 2; ++i) {
        const int c = i * 256 + tid;
        const int row = c >> 2, kb = (c & 3) * 8;
        gld_lds16(Bt + (size_t)(n0 + row) * K + kt + kb, (void*)(Bs[bi] + (size_t)(c & ~63) * 8));
      }
    } else {
      const int c = tid;                          // B: 256 chunks, 1/thread
      const int row = c >> 2, kb = (c & 3) * 8;
      gld_lds16(Bt + (size_t)(n0 + row) * K + kt + kb, (void*)(Bs[bi] + (size_t)(c & ~63) * 8));
    }
  };

  const int NT = K >> 5;                          // K-tiles of 32
  stage(0, 0); stage(1, 32);
  if constexpr (TN == 128) WAITV(4); else WAITV(3);   // tile0 landed
  __builtin_amdgcn_s_barrier();

  int bi = 0;
  for (int t = 0; t < NT; ++t) {
    int bs = bi + 2; if (bs >= 3) bs -= 3;
    const bool st = (t + 2 < NT);
    if (st) stage(bs, (t + 2) * 32);              // prefetch depth 2
    bf16x8 af[4], bfr[NFRAG];
    #pragma unroll
    for (int mi = 0; mi < 4; ++mi)
      af[mi] = *reinterpret_cast<const bf16x8*>(As[bi] + (wr * 64 + mi * 16 + r15) * 32 + g * 8);
    #pragma unroll
    for (int ni = 0; ni < NFRAG; ++ni)
      bfr[ni] = *reinterpret_cast<const bf16x8*>(Bs[bi] + (wc * (TN / 2) + ni * 16 + r15) * 32 + g * 8);
    __builtin_amdgcn_s_setprio(1);
    #pragma unroll
    for (int mi = 0; mi < 4; ++mi)
      #pragma unroll
      for (int ni = 0; ni < NFRAG; ++ni)
        acc[mi][ni] = __builtin_amdgcn_mfma_f32_16x16x32_bf16(af[mi], bfr[ni], acc[mi][ni], 0, 0, 0);
    __builtin_amdgcn_s_setprio(0);
    if (t + 1 < NT) {
      if (st) { if constexpr (TN == 128) WAITV(4); else WAITV(3); }
      else    { WAITV(0); }                       // tile t+1 landed
      __builtin_amdgcn_s_barrier();
    }
    bi = (bi + 1 == 3) ? 0 : bi + 1;
  }

  // Epilogue. C/D layout: col = lane&15, row = (lane>>4)*4 + reg  [m89/m91]
  #pragma unroll
  for (int mi = 0; mi < 4; ++mi) {
    #pragma unroll
    for (int ni = 0; ni < NFRAG; ++ni) {
      const int mb = m0 + wr * 64 + mi * 16 + g * 4;    // 4 consecutive m
      const int n  = n0 + wc * (TN / 2) + ni * 16 + r15;
      if (MODE == 0) {
        const int w = n >> 10, nn = n & 1023;           // wave-uniform per frag
        const int h = nn >> 6, dh = nn & 63;
        const int b = mb >> 11, s = mb & 2047;
        const size_t bh = (size_t)(b * H_ + h);
        if (w == 2) {
          ushort4 pv;
          pv.x = f2bf(acc[mi][ni][0]); pv.y = f2bf(acc[mi][ni][1]);
          pv.z = f2bf(acc[mi][ni][2]); pv.w = f2bf(acc[mi][ni][3]);
          *reinterpret_cast<ushort4*>((unsigned short*)Vtb + (bh * DH_ + dh) * S_ + s) = pv;
        } else {
          #pragma unroll
          for (int rr = 0; rr < 4; ++rr) {
            float v = acc[mi][ni][rr];
            if (w == 0) v *= 0.022097086912079608f * 1.4426950408889634f;
            const __hip_bfloat16 hv = __float2bfloat16(v);
            if (w == 0) Qb[(bh * S_ + s + rr) * DH_ + dh] = hv;
            else        Kb[(bh * S_ + s + rr) * DH_ + dh] = hv;
          }
        }
      } else {
        #pragma unroll
        for (int rr = 0; rr < 4; ++rr)
          Out[(size_t)(mb + rr) * N + n] = acc[mi][ni][rr] + bias[n];
      }
    }
  }
}

// ---------------- flash attention (R8/R13-measured best: 42.5 us) ---------
// grid (B*H, S/64); bh FAST dim -> XCD affinity. qb = 31-blockIdx.y
// (heavy-first). 4 waves x 16 q, KVBLK=64, K/V double-buffered via
// global_load_lds (pre-swizzled source, rule #21). Swapped QK^T -> D[kv][q],
// lane-local fixed-max exp2 softmax, P via per-wave LDS, denom reduce once.
__global__ __launch_bounds__(256) void k_attn(
    const __hip_bfloat16* __restrict__ Qb,
    const __hip_bfloat16* __restrict__ Kb,
    const __hip_bfloat16* __restrict__ Vtb,
    __hip_bfloat16* __restrict__ Ctx)
{
  __shared__ __align__(16) __hip_bfloat16 Ks[2][64 * 64];
  __shared__ __align__(16) __hip_bfloat16 Vs[2][64 * 64];
  __shared__ __align__(16) unsigned short Pl[4][16 * 64];
  const int tid = threadIdx.x, lane = tid & 63, w = tid >> 6;
  const int r15 = lane & 15, g = lane >> 4;
  const int bh = blockIdx.x;
  const int b = bh >> 4, h = bh & 15;
  const int qb = 31 - blockIdx.y;
  const __hip_bfloat16* Qh = Qb  + (size_t)bh * S_ * DH_;
  const __hip_bfloat16* Kh = Kb  + (size_t)bh * S_ * DH_;
  const __hip_bfloat16* Vh = Vtb + (size_t)bh * DH_ * S_;
  char* PlW = (char*)&Pl[w][0];
  const int sw = (r15 & 7);
  const float FIXM = 4.0f;

  auto stage = [&](int bufi, int t) {
    const int kv0 = t * 64;
    #pragma unroll
    for (int i = 0; i < 2; ++i) {
      const int c = i * 256 + tid;
      const int r = c >> 3;
      const int scc = (c & 7) ^ (r & 7);
      const int cbase = i * 256 + w * 64;
      gld_lds16(Kh + (size_t)(kv0 + r) * DH_ + scc * 8, (void*)(Ks[bufi] + cbase * 8));
      gld_lds16(Vh + (size_t)r * S_ + kv0 + scc * 8,    (void*)(Vs[bufi] + cbase * 8));
    }
  };

  const int q = qb * 64 + w * 16 + r15;

  bf16x8 qf[2];
  #pragma unroll
  for (int ks = 0; ks < 2; ++ks)
    qf[ks] = *reinterpret_cast<const bf16x8*>(Qh + (size_t)q * DH_ + ks * 32 + g * 8);

  f32x4 of[4] = {};
  float lrow = 0.f;

  const int nt = qb + 1;
  stage(0, 0);
  __syncthreads();

  for (int t = 0; t < nt; ++t) {
    const int cur = t & 1;
    if (t + 1 < nt) stage(cur ^ 1, t + 1);
    const char* Kb_ = (const char*)Ks[cur];
    const char* Vb_ = (const char*)Vs[cur];
    const int kv0 = t * 64;

    f32x4 sf[4] = {};
    __builtin_amdgcn_s_setprio(1);
    #pragma unroll
    for (int ks = 0; ks < 2; ++ks)
      #pragma unroll
      for (int c = 0; c < 4; ++c) {
        bf16x8 kf = *reinterpret_cast<const bf16x8*>(
            Kb_ + (c * 16 + r15) * 128 + (((ks * 4 + g) ^ sw) * 16));
        sf[c] = __builtin_amdgcn_mfma_f32_16x16x32_bf16(kf, qf[ks], sf[c], 0, 0, 0);
      }
    __builtin_amdgcn_s_setprio(0);

    float pv[16];
    #pragma unroll
    for (int c = 0; c < 4; ++c)
      #pragma unroll
      for (int r = 0; r < 4; ++r)
        pv[c * 4 + r] = sf[c][r];
    if (t == qb) {
      #pragma unroll
      for (int c = 0; c < 4; ++c)
        #pragma unroll
        for (int r = 0; r < 4; ++r) {
          const int kv = kv0 + c * 16 + g * 4 + r;
          if (kv > q) pv[c * 4 + r] = -INFINITY;
        }
    }
    float pe[16];
    #pragma unroll
    for (int j = 0; j < 16; ++j) pe[j] = fexp2(pv[j] - FIXM);
    #pragma unroll
    for (int c = 0; c < 4; ++c) {
      ushort4 pw;
      pw.x = f2bf(pe[c * 4 + 0]); pw.y = f2bf(pe[c * 4 + 1]);
      pw.z = f2bf(pe[c * 4 + 2]); pw.w = f2bf(pe[c * 4 + 3]);
      const int chunk = (c * 2 + (g >> 1)) ^ sw;
      *reinterpret_cast<ushort4*>(PlW + r15 * 128 + chunk * 16 + (g & 1) * 8) = pw;
    }
    float s8[8], s4[4];
    #pragma unroll
    for (int j = 0; j < 8; ++j) s8[j] = pe[j] + pe[j + 8];
    #pragma unroll
    for (int j = 0; j < 4; ++j) s4[j] = s8[j] + s8[j + 4];
    lrow += (s4[0] + s4[1]) + (s4[2] + s4[3]);

    __builtin_amdgcn_s_setprio(1);
    #pragma unroll
    for (int ks = 0; ks < 2; ++ks) {
      bf16x8 pf = *reinterpret_cast<const bf16x8*>(
          PlW + r15 * 128 + (((ks * 4 + g) ^ sw) * 16));
      #pragma unroll
      for (int d = 0; d < 4; ++d) {
        bf16x8 vf = *reinterpret_cast<const bf16x8*>(
            Vb_ + (d * 16 + r15) * 128 + (((ks * 4 + g) ^ sw) * 16));
        of[d] = __builtin_amdgcn_mfma_f32_16x16x32_bf16(vf, pf, of[d], 0, 0, 0);
      }
    }
    __builtin_amdgcn_s_setprio(0);
    __syncthreads();
  }

  lrow += __shfl_xor(lrow, 16, 64);
  lrow += __shfl_xor(lrow, 32, 64);

  const float inv = 1.0f / lrow;
  unsigned short* Cp = (unsigned short*)Ctx + ((size_t)(b * S_ + q) * H_ + h) * DH_;
  #pragma unroll
  for (int d = 0; d < 4; ++d) {
    ushort4 ov;
    ov.x = f2bf(of[d][0] * inv); ov.y = f2bf(of[d][1] * inv);
    ov.z = f2bf(of[d][2] * inv); ov.w = f2bf(of[d][3] * inv);
    *reinterpret_cast<ushort4*>(Cp + d * 16 + g * 4) = ov;
  }
}

// --------------------------------- launch --------------------------------
extern "C" void kernel_launch(void* const* d_in, const int* in_sizes, int n_in,
                              void* d_out, int out_size, void* d_ws, size_t ws_size,
                              hipStream_t stream) {
  const float* x  = (const float*)d_in[0];
  const float* Wq = (const float*)d_in[1];
  const float* Wk = (const float*)d_in[2];
  const float* Wv = (const float*)d_in[3];
  const float* Wo = (const float*)d_in[4];
  const float* bo = (const float*)d_in[5];
  float* out = (float*)d_out;

  uint8_t* ws = (uint8_t*)d_ws;
  __hip_bfloat16* xb  = (__hip_bfloat16*)(ws);
  __hip_bfloat16* Wt3 = (__hip_bfloat16*)(ws + 8388608);
  __hip_bfloat16* Wot = (__hip_bfloat16*)(ws + 14680064);
  __hip_bfloat16* Qb  = (__hip_bfloat16*)(ws + 16777216);
  __hip_bfloat16* Kb  = (__hip_bfloat16*)(ws + 25165824);
  __hip_bfloat16* Vtb = (__hip_bfloat16*)(ws + 33554432);
  __hip_bfloat16* Ctx = (__hip_bfloat16*)(ws + 41943040);

  // fused prep: z=0..3 transpose Wq/Wk/Wv/Wo (64x64 tiles), z=4 convert x
  k_prep<<<dim3(16, 16, 5), dim3(32, 8), 0, stream>>>(x, Wq, Wk, Wv, Wo,
                                                      (unsigned short*)xb, Wt3, Wot);
  // fused QKV: A = xb [4096,1024], Bt = [Wq^T|Wk^T|Wv^T] [3072,1024]
  k_gemm_bt<0, 128><<<dim3(32, 24), 256, 0, stream>>>(xb, Wt3, Qb, Kb, Vtb, nullptr, nullptr,
                                                      4096, 3072, 1024);
  k_attn<<<dim3(32, 32), 256, 0, stream>>>(Qb, Kb, Vtb, Ctx);
  // out = Ctx @ Wo + bo  (fp32 out), tile 128x64 -> 512 blocks
  k_gemm_bt<1, 64><<<dim3(32, 16), 256, 0, stream>>>(Ctx, Wot, nullptr, nullptr, nullptr,
                                                     out, bo, 4096, 1024, 1024);
}